// Round 18
// baseline (45.385 us; speedup 1.0000x reference)
//
#include <hip/hip_runtime.h>
#include <hip/hip_bf16.h>

#define NUM_GT 25
#define NUM_PRED 40
#define PAD 32         // 128 B between global words

// ws u32 word offsets (each on its own 128B line):
//   GT_W(b), b=0..24 : g_gt(b) = sum |gt - b|     (SAD accumulators)
//   PR_W(p), p=0..39 : g_pr(p) = sum |pred - p|
//   OV_W(p), p=0..40 : overlap bitmask row p
#define GT_W(b)  ((b) * PAD)
#define PR_W(p)  ((25 + (p)) * PAD)
#define OV_W(p)  ((65 + (p)) * PAD)
#define WS_WORDS (106 * PAD)

#define GRID  1024
#define BLOCK 256
#define TILE  2048     // voxels per block-tile (8 KB per array)

#if defined(__has_builtin)
#  if __has_builtin(__builtin_amdgcn_sad_u8)
#    define SAD(A, W, K) (A) = __builtin_amdgcn_sad_u8((W), (K), (A))
#  endif
#endif
#ifndef SAD
#  define SAD(A, W, K) asm("v_sad_u8 %0, %1, %2, %0" : "+v"(A) : "v"(W), "s"(K))
#endif

#define AS1 __attribute__((address_space(1)))
#define AS3 __attribute__((address_space(3)))

#if defined(__has_builtin) && __has_builtin(__builtin_amdgcn_global_load_lds)
#define GLOAD(SRC, DST) \
    __builtin_amdgcn_global_load_lds((const AS1 unsigned*)(SRC), \
                                     (AS3 unsigned*)(DST), 16, 0, 0)
#else
#define GLOAD(SRC, DST) /* fallback: sync copy */ \
    (*(uint4*)((DST) + (threadIdx.x & 63) * 4) = *(const uint4*)(SRC))
#endif

// ---------------------------------------------------------------------------
// Barrier-free pipelined SAD histogram.
// Each wave stages and computes ITS OWN LDS quarter -> no cross-wave tile
// dependency -> no __syncthreads in the loop. Counted s_waitcnt vmcnt(4)
// keeps tile k+1's 4 loads IN FLIGHT across tile k's compute (T4: never
// vmcnt(0) in the main loop). R17's bug: __syncthreads == vmcnt(0) drain,
// which serialized every prior variant into a mem+compute convoy.
// ---------------------------------------------------------------------------
__global__ __launch_bounds__(BLOCK) void hist_kernel(
    const float* __restrict__ pred, const int* __restrict__ gt,
    unsigned* __restrict__ ws, int n)
{
    __shared__ unsigned lgt[2][TILE];        // 16 KB
    __shared__ unsigned lpr[2][TILE];        // 16 KB
    __shared__ unsigned sovl[64];
    __shared__ unsigned shist[66];

    const int tid  = threadIdx.x;
    const int lane = tid & 63;
    const int wid  = tid >> 6;

    if (tid < 64) sovl[tid] = 0u;
    if (tid < 66) shist[tid] = 0u;

    // acc[0..24]=g_gt(0..24); acc[25..64]=g_pr(0..39); acc[65] dummy pad
    unsigned acc[66];
    #pragma unroll
    for (int j = 0; j < 66; ++j) acc[j] = 0u;

    const unsigned* __restrict__ gu = (const unsigned*)gt;
    const unsigned* __restrict__ pu = (const unsigned*)pred;
    const int ntiles = n / TILE;                       // 8192 for 256^3
    const int nt = (ntiles > (int)blockIdx.x)
                 ? (ntiles - (int)blockIdx.x + GRID - 1) / GRID : 0;  // 8

    __syncthreads();                                   // sovl/shist init only

    // stage tile k (buffer k&1): 4 async gload_lds (gt x2, pred x2), 1KB each
    #define STAGE(K)                                                          \
    do {                                                                      \
        const size_t base = ((size_t)blockIdx.x + (size_t)(K) * GRID) * TILE  \
                          + wid * 512;                                        \
        const unsigned* sg = gu + base + lane * 4;                            \
        unsigned* dg = &lgt[(K) & 1][0] + wid * 512;                          \
        GLOAD(sg, dg); GLOAD(sg + 256, dg + 256);                             \
        const unsigned* sp = pu + base + lane * 4;                            \
        unsigned* dp = &lpr[(K) & 1][0] + wid * 512;                          \
        GLOAD(sp, dp); GLOAD(sp + 256, dp + 256);                             \
    } while (0)

    if (nt > 0) STAGE(0);
    if (nt > 1) STAGE(1);

    for (int k = 0; k < nt; ++k) {
        // tile k's 4 loads complete; tile k+1's 4 REMAIN IN FLIGHT
        if (k + 1 < nt) asm volatile("s_waitcnt vmcnt(4)" ::: "memory");
        else            asm volatile("s_waitcnt vmcnt(0)" ::: "memory");
        __builtin_amdgcn_sched_barrier(0);

        const uint4* g4 = (const uint4*)(&lgt[k & 1][0] + wid * 512);
        const uint4* p4 = (const uint4*)(&lpr[k & 1][0] + wid * 512);
        #pragma unroll
        for (int h = 0; h < 2; ++h) {
            uint4 gw = g4[h * 64 + lane];
            uint4 pw = p4[h * 64 + lane];
            unsigned b0 = (unsigned)__uint_as_float(pw.x);
            unsigned b1 = (unsigned)__uint_as_float(pw.y);
            unsigned b2 = (unsigned)__uint_as_float(pw.z);
            unsigned b3 = (unsigned)__uint_as_float(pw.w);

            atomicOr(&sovl[b0 & 63], 1u << (gw.x & 31));
            atomicOr(&sovl[b1 & 63], 1u << (gw.y & 31));
            atomicOr(&sovl[b2 & 63], 1u << (gw.z & 31));
            atomicOr(&sovl[b3 & 63], 1u << (gw.w & 31));

            unsigned G = gw.x | (gw.y << 8) | (gw.z << 16) | (gw.w << 24);
            unsigned P = b0 | (b1 << 8) | (b2 << 16) | (b3 << 24);
            #pragma unroll
            for (int b = 0; b < 25; ++b) {
                const unsigned K = (unsigned)(b * 0x01010101u);
                SAD(acc[b], G, K);
            }
            #pragma unroll
            for (int b = 0; b < 40; ++b) {
                const unsigned K = (unsigned)(b * 0x01010101u);
                SAD(acc[25 + b], P, K);
            }
        }

        if (k + 2 < nt) {
            // ds_reads of buffer (k&1) are complete before we overwrite it
            asm volatile("s_waitcnt lgkmcnt(0)" ::: "memory");
            __builtin_amdgcn_sched_barrier(0);
            STAGE(k + 2);
        }
    }
    #undef STAGE

    // defensive scalar tail (empty for 256^3)
    if (blockIdx.x == 0 && tid == 0) {
        for (int v = ntiles * TILE; v < n; ++v) {
            int p = (int)pred[v];
            int g = gt[v];
            for (int b = 0; b < 25; ++b) atomicAdd(&ws[GT_W(b)], (unsigned)abs(g - b));
            for (int b = 0; b < 40; ++b) atomicAdd(&ws[PR_W(b)], (unsigned)abs(p - b));
            atomicOr(&ws[OV_W(min(max(p, 0), NUM_PRED))], 1u << (g & 31));
        }
    }

    __syncthreads();     // everyone done with tiles; epilogue reuses lgt
    // ---- epilogue: pair-packed u16 tree; stash overlaid on dead lgt buffer
    // (per-lane acc <= 64 vox * 40 = 2560; halves <= 40960, u16-safe)
    unsigned (*stash)[16][34] = (unsigned(*)[16][34])(&lgt[0][0]);
    #pragma unroll
    for (int jp = 0; jp < 33; ++jp) {
        unsigned v = acc[2 * jp] | (acc[2 * jp + 1] << 16);
        v += __shfl_down(v, 32, 64);
        v += __shfl_down(v, 16, 64);
        if (lane < 16) stash[wid][lane][jp] = v;
    }
    __syncthreads();

    for (int i = tid; i < 33 * 16; i += BLOCK) {
        int jp = i >> 4, sl = i & 15;
        unsigned a = stash[0][sl][jp] + stash[1][sl][jp]
                   + stash[2][sl][jp] + stash[3][sl][jp];
        unsigned lo = a & 0xFFFFu, hi = a >> 16;
        lo += __shfl_down(lo, 8, 16);  hi += __shfl_down(hi, 8, 16);
        lo += __shfl_down(lo, 4, 16);  hi += __shfl_down(hi, 4, 16);
        lo += __shfl_down(lo, 2, 16);  hi += __shfl_down(hi, 2, 16);
        lo += __shfl_down(lo, 1, 16);  hi += __shfl_down(hi, 1, 16);
        if (sl == 0) {
            if (lo) atomicAdd(&shist[2 * jp], lo);
            if (hi && 2 * jp + 1 < 65) atomicAdd(&shist[2 * jp + 1], hi);
        }
    }
    __syncthreads();

    for (int i = tid; i < 65; i += BLOCK) {
        unsigned s = shist[i];
        if (s) atomicAdd(&ws[i * PAD], s);
    }
    if (tid < 41) {
        unsigned v = sovl[tid];
        if (v) atomicOr(&ws[OV_W(tid)], v);
    }
}

// ---------------------------------------------------------------------------
// Finisher: second-difference count extraction (exact int64) + fp64 dice
// (proven absmax = 0, rounds 6-17).
// ---------------------------------------------------------------------------
__global__ __launch_bounds__(64) void finish_kernel(
    const unsigned* __restrict__ ws, float* __restrict__ out, int n)
{
    __shared__ long long gg[25], gp[40], psz[41];
    __shared__ unsigned ov[41];
    const int lane = threadIdx.x;
    if (lane < 25) gg[lane] = (long long)ws[GT_W(lane)];
    if (lane < 40) gp[lane] = (long long)ws[PR_W(lane)];
    if (lane < 41) ov[lane] = ws[OV_W(lane)];
    __syncthreads();

    const long long N = n, Sg = gg[0], Sp = gp[0];

    if (lane < 41) {                         // pred_sizes[P], P = lane
        int P = lane;
        long long f;
        if (P == 0)       f = (N - gp[0] + gp[1]) / 2;
        else if (P <= 38) f = (gp[P - 1] - 2 * gp[P] + gp[P + 1]) / 2;
        else if (P == 39) f = (gp[38] - 2 * gp[39] + (40 * N - Sp)) / 2;
        else              f = (gp[39] - 39 * N + Sp) / 2;   // P = 40
        psz[P] = f;
    }
    __syncthreads();

    double dice = 0.0;
    int present = 0;
    if (lane < 25) {                         // gt component label L = lane+1
        int L = lane + 1;
        long long gs;
        if (L <= 23)      gs = (gg[L - 1] - 2 * gg[L] + gg[L + 1]) / 2;
        else if (L == 24) gs = (gg[23] - 2 * gg[24] + (25 * N - Sg)) / 2;
        else              gs = (gg[24] - 24 * N + Sg) / 2;  // L = 25
        if (gs > 0) {
            present = 1;
            double un = 0.0;
            const unsigned bit = 1u << L;
            for (int p = 0; p < 41; ++p)
                if (ov[p] & bit) un += (double)psz[p];
            dice = 2.0 * (double)gs / (un + (double)gs + 1.0);
        }
    }
    int fp = 0;
    if (lane < 41) {
        if (psz[lane] > 0 && (ov[lane] & 0x3FFFFFEu) == 0) fp = 1;
    }

    int num_gt = __popcll(__ballot(present != 0));
    int nfp    = __popcll(__ballot(fp != 0));
    #pragma unroll
    for (int o = 32; o >= 1; o >>= 1) dice += __shfl_xor(dice, o, 64);

    if (lane == 0) out[0] = (float)(dice / (double)(num_gt + nfp));
}

extern "C" void kernel_launch(void* const* d_in, const int* in_sizes, int n_in,
                              void* d_out, int out_size, void* d_ws, size_t ws_size,
                              hipStream_t stream) {
    const float* pred = (const float*)d_in[0];
    const int* gt = (const int*)d_in[1];
    float* out = (float*)d_out;
    unsigned* ws = (unsigned*)d_ws;
    const int n = in_sizes[0];

    hipMemsetAsync(ws, 0, WS_WORDS * sizeof(unsigned), stream);

    hist_kernel<<<GRID, BLOCK, 0, stream>>>(pred, gt, ws, n);
    finish_kernel<<<1, 64, 0, stream>>>(ws, out, n);
}

// Round 19
// 45.335 us; speedup vs baseline: 1.0011x; 1.0011x over previous
//
#include <hip/hip_runtime.h>
#include <hip/hip_bf16.h>

#define NUM_GT 25
#define NUM_PRED 40
#define PAD 32         // 128 B between global words

// ws u32 word offsets (each on its own 128B line):
//   GT_W(b), b=0..24 : g_gt(b) = sum |gt - b|     (SAD accumulators)
//   PR_W(p), p=0..39 : g_pr(p) = sum |pred - p|
//   OV_W(p), p=0..40 : overlap bitmask row p
#define GT_W(b)  ((b) * PAD)
#define PR_W(p)  ((25 + (p)) * PAD)
#define OV_W(p)  ((65 + (p)) * PAD)
#define WS_WORDS (106 * PAD)

#define GRID  1024
#define BLOCK 256
#define TILE  2048     // voxels per block-tile (8 KB per array)

#if defined(__has_builtin)
#  if __has_builtin(__builtin_amdgcn_sad_u8)
#    define SAD(A, W, K) (A) = __builtin_amdgcn_sad_u8((W), (K), (A))
#  endif
#endif
#ifndef SAD
#  define SAD(A, W, K) asm("v_sad_u8 %0, %1, %2, %0" : "+v"(A) : "v"(W), "s"(K))
#endif

#define AS1 __attribute__((address_space(1)))
#define AS3 __attribute__((address_space(3)))

#if defined(__has_builtin) && __has_builtin(__builtin_amdgcn_global_load_lds)
#define GLOAD(SRC, DST) \
    __builtin_amdgcn_global_load_lds((const AS1 unsigned*)(SRC), \
                                     (AS3 unsigned*)(DST), 16, 0, 0)
#else
#define GLOAD(SRC, DST) \
    (*(uint4*)((DST) + (threadIdx.x & 63) * 4) = *(const uint4*)(SRC))
#endif

// ---------------------------------------------------------------------------
// Issue-order-pipelined SAD histogram.
// Per iteration: (1) ds_read tile k -> regs. The compiler's conservative
// s_waitcnt vmcnt(0) lands HERE, where the only outstanding vmem ops are
// tile k's own 4 staging loads (tile k+1 not yet issued) -- so the drain is
// exactly the unavoidable data wait. (2) sched_barrier. (3) issue async
// STAGE(k+1) into the other buffer. (4) sched_barrier. (5) SAD block on
// registers while tile k+1 streams from HBM underneath.
// R17 failed because __syncthreads drains vmcnt; R18 failed because the
// compiler re-inserted vmcnt(0) at the ds_read after my counted wait.
// ---------------------------------------------------------------------------
__global__ __launch_bounds__(BLOCK) void hist_kernel(
    const float* __restrict__ pred, const int* __restrict__ gt,
    unsigned* __restrict__ ws, int n)
{
    __shared__ unsigned lgt[2][TILE];        // 16 KB
    __shared__ unsigned lpr[2][TILE];        // 16 KB
    __shared__ unsigned sovl[64];
    __shared__ unsigned shist[66];

    const int tid  = threadIdx.x;
    const int lane = tid & 63;
    const int wid  = tid >> 6;

    if (tid < 64) sovl[tid] = 0u;
    if (tid < 66) shist[tid] = 0u;

    // acc[0..24]=g_gt(0..24); acc[25..64]=g_pr(0..39); acc[65] dummy pad
    unsigned acc[66];
    #pragma unroll
    for (int j = 0; j < 66; ++j) acc[j] = 0u;

    const unsigned* __restrict__ gu = (const unsigned*)gt;
    const unsigned* __restrict__ pu = (const unsigned*)pred;
    const int ntiles = n / TILE;                       // 8192 for 256^3
    const int nt = (ntiles > (int)blockIdx.x)
                 ? (ntiles - (int)blockIdx.x + GRID - 1) / GRID : 0;  // 8

    __syncthreads();                                   // sovl/shist init only

    // stage tile k (buffer k&1): 4 async gload_lds (gt x2, pred x2), 1KB each
    #define STAGE(K)                                                          \
    do {                                                                      \
        const size_t base = ((size_t)blockIdx.x + (size_t)(K) * GRID) * TILE  \
                          + wid * 512;                                        \
        const unsigned* sg = gu + base + lane * 4;                            \
        unsigned* dg = &lgt[(K) & 1][0] + wid * 512;                          \
        GLOAD(sg, dg); GLOAD(sg + 256, dg + 256);                             \
        const unsigned* sp = pu + base + lane * 4;                            \
        unsigned* dp = &lpr[(K) & 1][0] + wid * 512;                          \
        GLOAD(sp, dp); GLOAD(sp + 256, dp + 256);                             \
    } while (0)

    if (nt > 0) STAGE(0);

    for (int k = 0; k < nt; ++k) {
        // ---- (1) pull tile k into registers; compiler's vmcnt(0) lands
        //      here, covering ONLY tile k's loads (k+1 not yet issued) ----
        const uint4* g4 = (const uint4*)(&lgt[k & 1][0] + wid * 512);
        const uint4* p4 = (const uint4*)(&lpr[k & 1][0] + wid * 512);
        uint4 gw0 = g4[lane],      pw0 = p4[lane];
        uint4 gw1 = g4[64 + lane], pw1 = p4[64 + lane];
        __builtin_amdgcn_sched_barrier(0);

        // ---- (3) issue next tile; streams during the SAD block ----
        if (k + 1 < nt) STAGE(k + 1);
        __builtin_amdgcn_sched_barrier(0);

        // ---- (5) compute tile k from registers ----
        {
            unsigned b0 = (unsigned)__uint_as_float(pw0.x);
            unsigned b1 = (unsigned)__uint_as_float(pw0.y);
            unsigned b2 = (unsigned)__uint_as_float(pw0.z);
            unsigned b3 = (unsigned)__uint_as_float(pw0.w);
            atomicOr(&sovl[b0 & 63], 1u << (gw0.x & 31));
            atomicOr(&sovl[b1 & 63], 1u << (gw0.y & 31));
            atomicOr(&sovl[b2 & 63], 1u << (gw0.z & 31));
            atomicOr(&sovl[b3 & 63], 1u << (gw0.w & 31));
            unsigned G = gw0.x | (gw0.y << 8) | (gw0.z << 16) | (gw0.w << 24);
            unsigned P = b0 | (b1 << 8) | (b2 << 16) | (b3 << 24);
            #pragma unroll
            for (int b = 0; b < 25; ++b) {
                const unsigned K = (unsigned)(b * 0x01010101u);
                SAD(acc[b], G, K);
            }
            #pragma unroll
            for (int b = 0; b < 40; ++b) {
                const unsigned K = (unsigned)(b * 0x01010101u);
                SAD(acc[25 + b], P, K);
            }
        }
        {
            unsigned b0 = (unsigned)__uint_as_float(pw1.x);
            unsigned b1 = (unsigned)__uint_as_float(pw1.y);
            unsigned b2 = (unsigned)__uint_as_float(pw1.z);
            unsigned b3 = (unsigned)__uint_as_float(pw1.w);
            atomicOr(&sovl[b0 & 63], 1u << (gw1.x & 31));
            atomicOr(&sovl[b1 & 63], 1u << (gw1.y & 31));
            atomicOr(&sovl[b2 & 63], 1u << (gw1.z & 31));
            atomicOr(&sovl[b3 & 63], 1u << (gw1.w & 31));
            unsigned G = gw1.x | (gw1.y << 8) | (gw1.z << 16) | (gw1.w << 24);
            unsigned P = b0 | (b1 << 8) | (b2 << 16) | (b3 << 24);
            #pragma unroll
            for (int b = 0; b < 25; ++b) {
                const unsigned K = (unsigned)(b * 0x01010101u);
                SAD(acc[b], G, K);
            }
            #pragma unroll
            for (int b = 0; b < 40; ++b) {
                const unsigned K = (unsigned)(b * 0x01010101u);
                SAD(acc[25 + b], P, K);
            }
        }
    }
    #undef STAGE

    // defensive scalar tail (empty for 256^3)
    if (blockIdx.x == 0 && tid == 0) {
        for (int v = ntiles * TILE; v < n; ++v) {
            int p = (int)pred[v];
            int g = gt[v];
            for (int b = 0; b < 25; ++b) atomicAdd(&ws[GT_W(b)], (unsigned)abs(g - b));
            for (int b = 0; b < 40; ++b) atomicAdd(&ws[PR_W(b)], (unsigned)abs(p - b));
            atomicOr(&ws[OV_W(min(max(p, 0), NUM_PRED))], 1u << (g & 31));
        }
    }

    __syncthreads();     // all tiles done; epilogue reuses lgt
    // ---- epilogue: pair-packed u16 tree; stash overlaid on dead lgt buffer
    // (per-lane acc <= 64 vox * 40 = 2560; halves <= 40960, u16-safe)
    unsigned (*stash)[16][34] = (unsigned(*)[16][34])(&lgt[0][0]);
    #pragma unroll
    for (int jp = 0; jp < 33; ++jp) {
        unsigned v = acc[2 * jp] | (acc[2 * jp + 1] << 16);
        v += __shfl_down(v, 32, 64);
        v += __shfl_down(v, 16, 64);
        if (lane < 16) stash[wid][lane][jp] = v;
    }
    __syncthreads();

    for (int i = tid; i < 33 * 16; i += BLOCK) {
        int jp = i >> 4, sl = i & 15;
        unsigned a = stash[0][sl][jp] + stash[1][sl][jp]
                   + stash[2][sl][jp] + stash[3][sl][jp];
        unsigned lo = a & 0xFFFFu, hi = a >> 16;
        lo += __shfl_down(lo, 8, 16);  hi += __shfl_down(hi, 8, 16);
        lo += __shfl_down(lo, 4, 16);  hi += __shfl_down(hi, 4, 16);
        lo += __shfl_down(lo, 2, 16);  hi += __shfl_down(hi, 2, 16);
        lo += __shfl_down(lo, 1, 16);  hi += __shfl_down(hi, 1, 16);
        if (sl == 0) {
            if (lo) atomicAdd(&shist[2 * jp], lo);
            if (hi && 2 * jp + 1 < 65) atomicAdd(&shist[2 * jp + 1], hi);
        }
    }
    __syncthreads();

    for (int i = tid; i < 65; i += BLOCK) {
        unsigned s = shist[i];
        if (s) atomicAdd(&ws[i * PAD], s);
    }
    if (tid < 41) {
        unsigned v = sovl[tid];
        if (v) atomicOr(&ws[OV_W(tid)], v);
    }
}

// ---------------------------------------------------------------------------
// Finisher: second-difference count extraction (exact int64) + fp64 dice
// (proven absmax = 0, rounds 6-18).
// ---------------------------------------------------------------------------
__global__ __launch_bounds__(64) void finish_kernel(
    const unsigned* __restrict__ ws, float* __restrict__ out, int n)
{
    __shared__ long long gg[25], gp[40], psz[41];
    __shared__ unsigned ov[41];
    const int lane = threadIdx.x;
    if (lane < 25) gg[lane] = (long long)ws[GT_W(lane)];
    if (lane < 40) gp[lane] = (long long)ws[PR_W(lane)];
    if (lane < 41) ov[lane] = ws[OV_W(lane)];
    __syncthreads();

    const long long N = n, Sg = gg[0], Sp = gp[0];

    if (lane < 41) {                         // pred_sizes[P], P = lane
        int P = lane;
        long long f;
        if (P == 0)       f = (N - gp[0] + gp[1]) / 2;
        else if (P <= 38) f = (gp[P - 1] - 2 * gp[P] + gp[P + 1]) / 2;
        else if (P == 39) f = (gp[38] - 2 * gp[39] + (40 * N - Sp)) / 2;
        else              f = (gp[39] - 39 * N + Sp) / 2;   // P = 40
        psz[P] = f;
    }
    __syncthreads();

    double dice = 0.0;
    int present = 0;
    if (lane < 25) {                         // gt component label L = lane+1
        int L = lane + 1;
        long long gs;
        if (L <= 23)      gs = (gg[L - 1] - 2 * gg[L] + gg[L + 1]) / 2;
        else if (L == 24) gs = (gg[23] - 2 * gg[24] + (25 * N - Sg)) / 2;
        else              gs = (gg[24] - 24 * N + Sg) / 2;  // L = 25
        if (gs > 0) {
            present = 1;
            double un = 0.0;
            const unsigned bit = 1u << L;
            for (int p = 0; p < 41; ++p)
                if (ov[p] & bit) un += (double)psz[p];
            dice = 2.0 * (double)gs / (un + (double)gs + 1.0);
        }
    }
    int fp = 0;
    if (lane < 41) {
        if (psz[lane] > 0 && (ov[lane] & 0x3FFFFFEu) == 0) fp = 1;
    }

    int num_gt = __popcll(__ballot(present != 0));
    int nfp    = __popcll(__ballot(fp != 0));
    #pragma unroll
    for (int o = 32; o >= 1; o >>= 1) dice += __shfl_xor(dice, o, 64);

    if (lane == 0) out[0] = (float)(dice / (double)(num_gt + nfp));
}

extern "C" void kernel_launch(void* const* d_in, const int* in_sizes, int n_in,
                              void* d_out, int out_size, void* d_ws, size_t ws_size,
                              hipStream_t stream) {
    const float* pred = (const float*)d_in[0];
    const int* gt = (const int*)d_in[1];
    float* out = (float*)d_out;
    unsigned* ws = (unsigned*)d_ws;
    const int n = in_sizes[0];

    hipMemsetAsync(ws, 0, WS_WORDS * sizeof(unsigned), stream);

    hist_kernel<<<GRID, BLOCK, 0, stream>>>(pred, gt, ws, n);
    finish_kernel<<<1, 64, 0, stream>>>(ws, out, n);
}